// Round 8
// baseline (225.172 us; speedup 1.0000x reference)
//
#include <hip/hip_runtime.h>
#include <hip/hip_fp16.h>
#include <math.h>

#define IMG_H 512
#define IMG_W 512
#define NPLANES 48            // 16 * 3
#define RAD 5
#define TAPS 11
#define CHUNK 16              // 512/16 = 32 row-blocks; unrolls as 11 + 5 (static ring phase)
#define SBUF 80               // 74 fp16x2 entries used, padded

// Compiler-only fences for wave-private LDS (cross-lane dep invisible to alias
// analysis — R4 failed without them; HW in-order DS within a wave is fine).
#define WAVE_FENCE_WAR()  __asm__ __volatile__("" ::: "memory")
#define WAVE_FENCE_RAW()  __asm__ __volatile__("s_waitcnt lgkmcnt(0)" ::: "memory")

struct GaussPk { unsigned w[TAPS]; float wf[TAPS]; };  // fp16 broadcast-packed + fp32

__device__ __forceinline__ unsigned h2bits(__half2 h) { return __builtin_bit_cast(unsigned, h); }
__device__ __forceinline__ __half2  bits2h(unsigned u) { return __builtin_bit_cast(__half2, u); }

// Journal:
//  - R2: launch_bounds(256,6) -> 40-VGPR cap -> ring spilled. Keep (256,4).
//  - R3: per-row __syncthreads lockstep -> 42% VALUBusy. R5: wave-autonomous strips -> 70%.
//  - R6: pk_fma_f32 only -12%: CDNA4 packed fp32 is NOT double-rate (157TF = scalar rate).
//  - R7: fp16x2 convs: geometry correct but absmax 9.77e-4 — sigma cancellation
//    (conv(x^2)~0.33 minus mu^2~0.25) amplifies fp16 accumulation error.
//  - R8: center at c=0.5 (exact). conv quantities of a'=a-0.5: cancellation 75%->4%.
//    Recover reference mu/sigma in fp32 epilogue; borders need W = Wc(x)*Wr(y)
//    (in-bounds weight mass, separable): mu = m + 0.5W; sg = P + mu - 0.25W - mu^2;
//    sg12 = P12 + 0.5(mu1+mu2) - 0.25W - mu1mu2. Interior (W=1) == R7 identities.
__global__ __launch_bounds__(256, 4)
void ssim_main(const float* __restrict__ img1, const float* __restrict__ img2,
               double* __restrict__ sum_ws, GaussPk gw) {
    // per-wave private row planes: entry i = (x[c0-5+i], x[c0+59+i]) as fp16x2, centered
    __shared__ unsigned planes[4][2][SBUF];
    __shared__ float wsum[4];

    const int tid  = threadIdx.x;
    const int wid  = tid >> 6;          // wave 0..3 -> 128-col strip
    const int lane = tid & 63;
    const int c0   = wid * 128;         // strip base col (grid.x == 1)
    const int y0   = blockIdx.y * CHUNK;
    const size_t pbase = (size_t)blockIdx.z * (IMG_H * IMG_W);
    const float* p1 = img1 + pbase;
    const float* p2 = img2 + pbase;
    unsigned* ap = planes[wid][0];
    unsigned* bp = planes[wid][1];

    // hoisted column indices/predicates (lane's LDS entries: lane and 64+lane)
    const int g0 = c0 - RAD + lane;            // may be <0 for wave 0
    const bool q0 = (g0 >= 0);                 // right side always <512
    const int g1 = c0 + 59 + lane;             // always in [59,506]
    const int g2 = c0 + 123 + lane;            // tail entries, lanes 0..9
    const bool q2 = (lane < 2 * RAD) && (g2 < IMG_W);

    // per-lane column weight mass for the two output columns (once per kernel)
    const int x1 = c0 + lane, x2 = c0 + 64 + lane;
    float Wc1 = 0.f, Wc2 = 0.f;
    #pragma unroll
    for (int d = 0; d < TAPS; ++d) {
        if ((unsigned)(x1 + d - RAD) < IMG_W) Wc1 += gw.wf[d];
        if ((unsigned)(x2 + d - RAD) < IMG_W) Wc2 += gw.wf[d];
    }

    // register ring: hconv results, fp16x2 = (col c0+lane, col c0+64+lane)
    __half2 rA[TAPS], rB[TAPS], rAA[TAPS], rBB[TAPS], rAB[TAPS];
    const __half2 hz = __float2half2_rn(0.0f);

    // fp32 prefetch regs for next row (CENTERED values; pad stays 0)
    float pa0, pa1, pa2, pb0, pb1, pb2;

    auto load_regs = [&](int r) {
        pa0 = pa1 = pa2 = pb0 = pb1 = pb2 = 0.f;
        if (r >= 0 && r < IMG_H) {              // wave-uniform
            const float* r1 = p1 + (size_t)r * IMG_W;
            const float* r2 = p2 + (size_t)r * IMG_W;
            if (q0) { pa0 = r1[g0] - 0.5f; pb0 = r2[g0] - 0.5f; }
            pa1 = r1[g1] - 0.5f; pb1 = r2[g1] - 0.5f;
            if (q2) { pa2 = r1[g2] - 0.5f; pb2 = r2[g2] - 0.5f; }
        }
    };

    auto store_lds = [&]() {
        WAVE_FENCE_WAR();
        ap[lane] = h2bits(__float22half2_rn(make_float2(pa0, pa1)));
        bp[lane] = h2bits(__float22half2_rn(make_float2(pb0, pb1)));
        if (lane < 2 * RAD) {                   // entry 64+lane = (x[c0+59+l], x[c0+123+l])
            ap[64 + lane] = h2bits(__float22half2_rn(make_float2(pa1, pa2)));
            bp[64 + lane] = h2bits(__float22half2_rn(make_float2(pb1, pb2)));
        }
        WAVE_FENCE_RAW();
    };

    // packed hconv: per tap 5 hfma2 + 3 hmul2 + 2 ds_read_b32 (covers BOTH cols)
    auto hconv = [&](int r, __half2& oA, __half2& oB, __half2& oAA, __half2& oBB, __half2& oAB) {
        __half2 hA = hz, hB = hz, hAA = hz, hBB = hz, hAB = hz;
        if (r >= 0 && r < IMG_H) {              // wave-uniform: padded rows are zero
            #pragma unroll
            for (int d = 0; d < TAPS; ++d) {
                __half2 va = bits2h(ap[lane + d]);
                __half2 vb = bits2h(bp[lane + d]);
                __half2 wv = bits2h(gw.w[d]);
                hA  = __hfma2(wv, va, hA);
                hB  = __hfma2(wv, vb, hB);
                hAA = __hfma2(wv, __hmul2(va, va), hAA);
                hBB = __hfma2(wv, __hmul2(vb, vb), hBB);
                hAB = __hfma2(wv, __hmul2(va, vb), hAB);
            }
        }
        oA = hA; oB = hB; oAA = hAA; oBB = hBB; oAB = hAB;
    };

    // ---- prologue: h-rows 0..9 (global rows y0-5 .. y0+4) -> ring slots 0..9
    load_regs(y0 - RAD);
    #pragma unroll
    for (int k = 0; k < TAPS - 1; ++k) {
        const int r = y0 - RAD + k;
        store_lds();
        load_regs(r + 1);                       // next row's loads in flight during hconv
        hconv(r, rA[k], rB[k], rAA[k], rBB[k], rAB[k]);
    }

    const float C1v = 0.0001f;  // 0.01^2
    const float C2v = 0.0009f;  // 0.03^2
    float acc = 0.f;

    // ---- main: CHUNK output rows; fully unrolled (11 + 5), static ring indices
    #pragma unroll
    for (int kk = 0; kk < CHUNK; kk += TAPS) {
        #pragma unroll
        for (int j = 0; j < TAPS; ++j) {
            if (kk + j < CHUNK) {
                const int rowc = kk + j;                    // 0..CHUNK-1
                const int r = y0 + RAD + rowc;              // staged input row
                store_lds();                                // publish prefetched row r
                load_regs(r + 1);                           // issue loads for row r+1 NOW
                hconv(r, rA[(rowc + 10) % TAPS], rB[(rowc + 10) % TAPS],
                      rAA[(rowc + 10) % TAPS], rBB[(rowc + 10) % TAPS],
                      rAB[(rowc + 10) % TAPS]);

                // packed vertical conv: 5 hfma2 per tap for both columns
                __half2 sA = hz, sB = hz, sAA = hz, sBB = hz, sAB = hz;
                #pragma unroll
                for (int t = 0; t < TAPS; ++t) {
                    const int s = (rowc + t) % TAPS;        // static after unroll
                    __half2 wv = bits2h(gw.w[t]);
                    sA  = __hfma2(wv, rA[s],  sA);
                    sB  = __hfma2(wv, rB[s],  sB);
                    sAA = __hfma2(wv, rAA[s], sAA);
                    sBB = __hfma2(wv, rBB[s], sBB);
                    sAB = __hfma2(wv, rAB[s], sAB);
                }

                // row weight mass (wave-uniform)
                const int y = y0 + rowc;
                float Wr = 0.f;
                #pragma unroll
                for (int t = 0; t < TAPS; ++t)
                    if ((unsigned)(y + t - RAD) < IMG_H) Wr += gw.wf[t];

                // fp32 epilogue with centering recovery, both pixels
                #pragma unroll
                for (int px = 0; px < 2; ++px) {
                    float m1  = px ? __high2float(sA)  : __low2float(sA);
                    float m2  = px ? __high2float(sB)  : __low2float(sB);
                    float P11 = px ? __high2float(sAA) : __low2float(sAA);
                    float P22 = px ? __high2float(sBB) : __low2float(sBB);
                    float P12 = px ? __high2float(sAB) : __low2float(sAB);
                    float W   = (px ? Wc2 : Wc1) * Wr;
                    float mu1 = fmaf(0.5f, W, m1);
                    float mu2 = fmaf(0.5f, W, m2);
                    float qW  = 0.25f * W;
                    float mu1sq = mu1 * mu1, mu2sq = mu2 * mu2, mu12 = mu1 * mu2;
                    float sg1  = P11 + mu1 - qW - mu1sq;
                    float sg2  = P22 + mu2 - qW - mu2sq;
                    float sg12 = P12 + 0.5f * (mu1 + mu2) - qW - mu12;
                    float num = (2.f * mu12 + C1v) * (2.f * sg12 + C2v);
                    float den = (mu1sq + mu2sq + C1v) * (sg1 + sg2 + C2v);
                    acc += num * __builtin_amdgcn_rcpf(den);
                }
            }
        }
    }

    // wave (64-lane) shuffle reduce -> block partials -> one atomic per block
    #pragma unroll
    for (int off = 32; off > 0; off >>= 1) acc += __shfl_down(acc, off, 64);
    if (lane == 0) wsum[wid] = acc;
    __syncthreads();                   // only block barrier in the kernel
    if (tid == 0) {
        double s = (double)wsum[0] + (double)wsum[1] + (double)wsum[2] + (double)wsum[3];
        atomicAdd(sum_ws, s);
    }
}

__global__ void ssim_finalize(const double* __restrict__ sum_ws, float* __restrict__ out) {
    out[0] = (float)(sum_ws[0] * (1.0 / (double)(16.0 * 3.0 * 512.0 * 512.0)));
}

// host fp32 -> fp16 bits, round-to-nearest-even
static unsigned short f32_to_f16_rne(float f) {
    unsigned x; __builtin_memcpy(&x, &f, 4);
    unsigned sign = (x >> 16) & 0x8000u;
    int exp = (int)((x >> 23) & 0xffu) - 127 + 15;
    unsigned man = x & 0x7fffffu;
    if (exp <= 0) return (unsigned short)sign;
    unsigned h = sign | ((unsigned)exp << 10) | (man >> 13);
    unsigned rnd = man & 0x1fffu;
    if (rnd > 0x1000u || (rnd == 0x1000u && (h & 1u))) h++;
    return (unsigned short)h;
}

extern "C" void kernel_launch(void* const* d_in, const int* in_sizes, int n_in,
                              void* d_out, int out_size, void* d_ws, size_t ws_size,
                              hipStream_t stream) {
    const float* img1 = (const float*)d_in[0];
    const float* img2 = (const float*)d_in[1];
    float* out = (float*)d_out;
    double* ws = (double*)d_ws;

    hipMemsetAsync(ws, 0, sizeof(double), stream);

    // Gaussian weights in double -> fp16 broadcast-packed + fp32 kernarg
    GaussPk gw;
    double g[TAPS], s = 0.0;
    for (int i = 0; i < TAPS; ++i) {
        double x = (double)(i - TAPS / 2);
        g[i] = exp(-(x * x) / (2.0 * 1.5 * 1.5));
        s += g[i];
    }
    for (int i = 0; i < TAPS; ++i) {
        float wf = (float)(g[i] / s);
        gw.wf[i] = wf;
        unsigned short h = f32_to_f16_rne(wf);
        gw.w[i] = (unsigned)h | ((unsigned)h << 16);
    }

    // grid: 1 x 32 x 48 = 1536 blocks (6/CU, 24 waves/CU); 4 waves x 128-col strips
    dim3 grid(1, IMG_H / CHUNK, NPLANES);
    ssim_main<<<grid, 256, 0, stream>>>(img1, img2, ws, gw);
    ssim_finalize<<<1, 1, 0, stream>>>(ws, out);
}

// Round 9
// 222.865 us; speedup vs baseline: 1.0103x; 1.0103x over previous
//
#include <hip/hip_runtime.h>
#include <hip/hip_fp16.h>
#include <math.h>

#define IMG_H 512
#define IMG_W 512
#define NPLANES 48            // 16 * 3
#define RAD 5
#define TAPS 11
#define CHUNK 16              // rows/block = 11 + 5 (two static inner loops)
#define SBUF 80               // 74 fp16x2 entries used, padded

// Compiler-only fences for wave-private LDS (cross-lane dep invisible to alias
// analysis — R4 failed without them; HW in-order DS within a wave is fine).
#define WAVE_FENCE_WAR()  __asm__ __volatile__("" ::: "memory")
#define WAVE_FENCE_RAW()  __asm__ __volatile__("s_waitcnt lgkmcnt(0)" ::: "memory")

struct GaussPk { unsigned w[TAPS]; float wf[TAPS]; };  // fp16 broadcast-packed + fp32

__device__ __forceinline__ unsigned h2bits(__half2 h) { return __builtin_bit_cast(unsigned, h); }
__device__ __forceinline__ __half2  bits2h(unsigned u) { return __builtin_bit_cast(__half2, u); }

// Journal:
//  - R2: launch_bounds(256,6) -> 40-VGPR cap -> ring spilled. Keep (256,4).
//  - R3: per-row __syncthreads lockstep -> 42% VALUBusy. R5: wave-autonomous strips -> 70%.
//  - R6: pk_fma_f32 only -12%: CDNA4 packed fp32 NOT double-rate. fp16x2 IS.
//  - R7: fp16 convs of raw values: absmax 9.8e-4 (sigma cancellation ~75%).
//  - R8: centered at 0.5 (cancellation ~4%) + fp32 border-mass epilogue: accuracy
//    FIXED, but ring indices depended on outer-loop var (rowc=kk+j) -> outer
//    unroll declined -> dynamic %TAPS -> WHOLE RING DEMOTED TO SCRATCH
//    (WRITE_SIZE 48KB->52MB, 133us, VALUBusy 35%).
//  - R9: restore R6's load-bearing structure: ring phase depends ONLY on the
//    inner unrolled j. 16 rows = static loop of 11 + static loop of 5
//    (phase continuous: (11+j+k)%11 == (j+k)%11).
__global__ __launch_bounds__(256, 4)
void ssim_main(const float* __restrict__ img1, const float* __restrict__ img2,
               double* __restrict__ sum_ws, GaussPk gw) {
    // per-wave private row planes: entry i = (x[c0-5+i], x[c0+59+i]) as fp16x2, centered
    __shared__ unsigned planes[4][2][SBUF];
    __shared__ float wsum[4];

    const int tid  = threadIdx.x;
    const int wid  = tid >> 6;          // wave 0..3 -> 128-col strip
    const int lane = tid & 63;
    const int c0   = wid * 128;         // strip base col (grid.x == 1)
    const int y0   = blockIdx.y * CHUNK;
    const size_t pbase = (size_t)blockIdx.z * (IMG_H * IMG_W);
    const float* p1 = img1 + pbase;
    const float* p2 = img2 + pbase;
    unsigned* ap = planes[wid][0];
    unsigned* bp = planes[wid][1];

    // hoisted column indices/predicates (lane's LDS entries: lane and 64+lane)
    const int g0 = c0 - RAD + lane;            // may be <0 for wave 0
    const bool q0 = (g0 >= 0);                 // right side always <512
    const int g1 = c0 + 59 + lane;             // always in [59,506]
    const int g2 = c0 + 123 + lane;            // tail entries, lanes 0..9
    const bool q2 = (lane < 2 * RAD) && (g2 < IMG_W);

    // per-lane column weight mass for the two output columns (once per kernel)
    const int x1 = c0 + lane, x2 = c0 + 64 + lane;
    float Wc1 = 0.f, Wc2 = 0.f;
    #pragma unroll
    for (int d = 0; d < TAPS; ++d) {
        if ((unsigned)(x1 + d - RAD) < IMG_W) Wc1 += gw.wf[d];
        if ((unsigned)(x2 + d - RAD) < IMG_W) Wc2 += gw.wf[d];
    }

    // register ring: hconv results, fp16x2 = (col c0+lane, col c0+64+lane)
    __half2 rA[TAPS], rB[TAPS], rAA[TAPS], rBB[TAPS], rAB[TAPS];
    const __half2 hz = __float2half2_rn(0.0f);

    // fp32 prefetch regs for next row (CENTERED values; pad stays 0)
    float pa0, pa1, pa2, pb0, pb1, pb2;

    auto load_regs = [&](int r) {
        pa0 = pa1 = pa2 = pb0 = pb1 = pb2 = 0.f;
        if (r >= 0 && r < IMG_H) {              // wave-uniform
            const float* r1 = p1 + (size_t)r * IMG_W;
            const float* r2 = p2 + (size_t)r * IMG_W;
            if (q0) { pa0 = r1[g0] - 0.5f; pb0 = r2[g0] - 0.5f; }
            pa1 = r1[g1] - 0.5f; pb1 = r2[g1] - 0.5f;
            if (q2) { pa2 = r1[g2] - 0.5f; pb2 = r2[g2] - 0.5f; }
        }
    };

    auto store_lds = [&]() {
        WAVE_FENCE_WAR();
        ap[lane] = h2bits(__float22half2_rn(make_float2(pa0, pa1)));
        bp[lane] = h2bits(__float22half2_rn(make_float2(pb0, pb1)));
        if (lane < 2 * RAD) {                   // entry 64+lane = (x[c0+59+l], x[c0+123+l])
            ap[64 + lane] = h2bits(__float22half2_rn(make_float2(pa1, pa2)));
            bp[64 + lane] = h2bits(__float22half2_rn(make_float2(pb1, pb2)));
        }
        WAVE_FENCE_RAW();
    };

    // packed hconv: per tap 5 hfma2 + 3 hmul2 + 2 ds_read_b32 (covers BOTH cols)
    auto hconv = [&](int r, __half2& oA, __half2& oB, __half2& oAA, __half2& oBB, __half2& oAB) {
        __half2 hA = hz, hB = hz, hAA = hz, hBB = hz, hAB = hz;
        if (r >= 0 && r < IMG_H) {              // wave-uniform: padded rows are zero
            #pragma unroll
            for (int d = 0; d < TAPS; ++d) {
                __half2 va = bits2h(ap[lane + d]);
                __half2 vb = bits2h(bp[lane + d]);
                __half2 wv = bits2h(gw.w[d]);
                hA  = __hfma2(wv, va, hA);
                hB  = __hfma2(wv, vb, hB);
                hAA = __hfma2(wv, __hmul2(va, va), hAA);
                hBB = __hfma2(wv, __hmul2(vb, vb), hBB);
                hAB = __hfma2(wv, __hmul2(va, vb), hAB);
            }
        }
        oA = hA; oB = hB; oAA = hAA; oBB = hBB; oAB = hAB;
    };

    // ---- prologue: h-rows 0..9 (global rows y0-5 .. y0+4) -> ring slots 0..9
    load_regs(y0 - RAD);
    #pragma unroll
    for (int k = 0; k < TAPS - 1; ++k) {
        const int r = y0 - RAD + k;
        store_lds();
        load_regs(r + 1);                       // next row's loads in flight during hconv
        hconv(r, rA[k], rB[k], rAA[k], rBB[k], rAB[k]);
    }

    const float C1v = 0.0001f;  // 0.01^2
    const float C2v = 0.0009f;  // 0.03^2
    float acc = 0.f;

    // one output row; ALL ring indices use the static inner-loop var jj only
    #define ROW_BODY(jj, rowc_)                                                    \
    {                                                                              \
        const int r = y0 + RAD + (rowc_);       /* staged input row */             \
        store_lds();                            /* publish prefetched row r */     \
        load_regs(r + 1);                       /* issue loads for row r+1 NOW */  \
        hconv(r, rA[((jj) + 10) % TAPS], rB[((jj) + 10) % TAPS],                   \
              rAA[((jj) + 10) % TAPS], rBB[((jj) + 10) % TAPS],                    \
              rAB[((jj) + 10) % TAPS]);                                            \
        __half2 sA = hz, sB = hz, sAA = hz, sBB = hz, sAB = hz;                    \
        _Pragma("unroll")                                                          \
        for (int t = 0; t < TAPS; ++t) {                                           \
            const int s = ((jj) + t) % TAPS;    /* static after unroll */          \
            __half2 wv = bits2h(gw.w[t]);                                          \
            sA  = __hfma2(wv, rA[s],  sA);                                         \
            sB  = __hfma2(wv, rB[s],  sB);                                         \
            sAA = __hfma2(wv, rAA[s], sAA);                                        \
            sBB = __hfma2(wv, rBB[s], sBB);                                        \
            sAB = __hfma2(wv, rAB[s], sAB);                                        \
        }                                                                          \
        const int y = y0 + (rowc_);                                                \
        float Wr = 0.f;                                                            \
        _Pragma("unroll")                                                          \
        for (int t = 0; t < TAPS; ++t)                                             \
            if ((unsigned)(y + t - RAD) < IMG_H) Wr += gw.wf[t];                   \
        _Pragma("unroll")                                                          \
        for (int px = 0; px < 2; ++px) {                                           \
            float m1  = px ? __high2float(sA)  : __low2float(sA);                  \
            float m2  = px ? __high2float(sB)  : __low2float(sB);                  \
            float P11 = px ? __high2float(sAA) : __low2float(sAA);                 \
            float P22 = px ? __high2float(sBB) : __low2float(sBB);                 \
            float P12 = px ? __high2float(sAB) : __low2float(sAB);                 \
            float W   = (px ? Wc2 : Wc1) * Wr;                                     \
            float mu1 = fmaf(0.5f, W, m1);                                         \
            float mu2 = fmaf(0.5f, W, m2);                                         \
            float qW  = 0.25f * W;                                                 \
            float mu1sq = mu1 * mu1, mu2sq = mu2 * mu2, mu12 = mu1 * mu2;          \
            float sg1  = P11 + mu1 - qW - mu1sq;                                   \
            float sg2  = P22 + mu2 - qW - mu2sq;                                   \
            float sg12 = P12 + 0.5f * (mu1 + mu2) - qW - mu12;                     \
            float num = (2.f * mu12 + C1v) * (2.f * sg12 + C2v);                   \
            float den = (mu1sq + mu2sq + C1v) * (sg1 + sg2 + C2v);                 \
            acc += num * __builtin_amdgcn_rcpf(den);                               \
        }                                                                          \
    }

    // ---- main: 16 output rows as 11 + 5; ring phase continuous across the
    // split because (11 + j + k) % 11 == (j + k) % 11.
    #pragma unroll
    for (int j = 0; j < TAPS; ++j)              // rows 0..10
        ROW_BODY(j, j)
    #pragma unroll
    for (int j = 0; j < CHUNK - TAPS; ++j)      // rows 11..15
        ROW_BODY(j, TAPS + j)
    #undef ROW_BODY

    // wave (64-lane) shuffle reduce -> block partials -> one atomic per block
    #pragma unroll
    for (int off = 32; off > 0; off >>= 1) acc += __shfl_down(acc, off, 64);
    if (lane == 0) wsum[wid] = acc;
    __syncthreads();                   // only block barrier in the kernel
    if (tid == 0) {
        double s = (double)wsum[0] + (double)wsum[1] + (double)wsum[2] + (double)wsum[3];
        atomicAdd(sum_ws, s);
    }
}

__global__ void ssim_finalize(const double* __restrict__ sum_ws, float* __restrict__ out) {
    out[0] = (float)(sum_ws[0] * (1.0 / (double)(16.0 * 3.0 * 512.0 * 512.0)));
}

// host fp32 -> fp16 bits, round-to-nearest-even
static unsigned short f32_to_f16_rne(float f) {
    unsigned x; __builtin_memcpy(&x, &f, 4);
    unsigned sign = (x >> 16) & 0x8000u;
    int exp = (int)((x >> 23) & 0xffu) - 127 + 15;
    unsigned man = x & 0x7fffffu;
    if (exp <= 0) return (unsigned short)sign;
    unsigned h = sign | ((unsigned)exp << 10) | (man >> 13);
    unsigned rnd = man & 0x1fffu;
    if (rnd > 0x1000u || (rnd == 0x1000u && (h & 1u))) h++;
    return (unsigned short)h;
}

extern "C" void kernel_launch(void* const* d_in, const int* in_sizes, int n_in,
                              void* d_out, int out_size, void* d_ws, size_t ws_size,
                              hipStream_t stream) {
    const float* img1 = (const float*)d_in[0];
    const float* img2 = (const float*)d_in[1];
    float* out = (float*)d_out;
    double* ws = (double*)d_ws;

    hipMemsetAsync(ws, 0, sizeof(double), stream);

    // Gaussian weights in double -> fp16 broadcast-packed + fp32 kernarg
    GaussPk gw;
    double g[TAPS], s = 0.0;
    for (int i = 0; i < TAPS; ++i) {
        double x = (double)(i - TAPS / 2);
        g[i] = exp(-(x * x) / (2.0 * 1.5 * 1.5));
        s += g[i];
    }
    for (int i = 0; i < TAPS; ++i) {
        float wf = (float)(g[i] / s);
        gw.wf[i] = wf;
        unsigned short h = f32_to_f16_rne(wf);
        gw.w[i] = (unsigned)h | ((unsigned)h << 16);
    }

    // grid: 1 x 32 x 48 = 1536 blocks (6/CU, 24 waves/CU); 4 waves x 128-col strips
    dim3 grid(1, IMG_H / CHUNK, NPLANES);
    ssim_main<<<grid, 256, 0, stream>>>(img1, img2, ws, gw);
    ssim_finalize<<<1, 1, 0, stream>>>(ws, out);
}

// Round 10
// 187.634 us; speedup vs baseline: 1.2001x; 1.1878x over previous
//
#include <hip/hip_runtime.h>
#include <hip/hip_fp16.h>
#include <math.h>

#define IMG_H 512
#define IMG_W 512
#define NPLANES 48            // 16 * 3
#define RAD 5
#define TAPS 11
#define CHUNK 33              // multiple of 11 -> static ring phase in inner loop
#define STRIP 64              // columns per wave (one autonomous wave per strip)
#define SBUF 80               // 74 entries used (64 + 2*RAD), padded

// Compiler-only fences for wave-private LDS (cross-lane dep invisible to alias
// analysis — R4 failed without them; HW in-order DS within a wave is fine).
#define WAVE_FENCE_WAR()  __asm__ __volatile__("" ::: "memory")
#define WAVE_FENCE_RAW()  __asm__ __volatile__("s_waitcnt lgkmcnt(0)" ::: "memory")

struct GaussPk { unsigned w[TAPS]; float wf[TAPS]; };  // fp16 broadcast-packed + fp32

__device__ __forceinline__ unsigned h2bits(__half2 h) { return __builtin_bit_cast(unsigned, h); }
__device__ __forceinline__ __half2  bits2h(unsigned u) { return __builtin_bit_cast(__half2, u); }
__device__ __forceinline__ __half2  swap16(__half2 h) {
    unsigned u = h2bits(h);
    return bits2h((u >> 16) | (u << 16));      // v_alignbit_b32
}

// Journal:
//  - R2: launch_bounds(256,6) -> 40-VGPR cap -> ring spilled. Keep (256,4).
//  - R3: per-row __syncthreads lockstep -> 42% VALUBusy. R5: wave-autonomous
//    64-col strips, no block barriers -> 70% VALUBusy, 77us.
//  - R6: v2f fp32 (CHUNK=33, outer runtime kk loop + inner static 11): 68.5us,
//    40 VGPR, WRITE 48KB. Packed fp32 is NOT double-rate on CDNA4.
//  - R7/R8: fp16 numerics fixed by centering at 0.5 + W-mass fp32 epilogue.
//  - R8/R9: flattening the whole 16-row main body straight-line -> 64 VGPR +
//    SCRATCH (WRITE 52-60MB, 133us) even with fully static ring indices.
//    The runtime outer loop is load-bearing: it bounds live ranges.
//  - R10: R6 skeleton EXACTLY + fp16 (a-0.5, b-0.5) packed per lane: every conv
//    op covers both images in one single-pass pk_f16 op; ring 55->33 VGPRs.
__global__ __launch_bounds__(256, 4)
void ssim_main(const float* __restrict__ img1, const float* __restrict__ img2,
               double* __restrict__ sum_ws, GaussPk gw) {
    __shared__ unsigned srow[4][SBUF];   // per-wave row: (a-.5, b-.5) fp16x2 per col
    __shared__ float wsum[4];

    const int tid  = threadIdx.x;
    const int wid  = tid >> 6;          // wave id 0..3
    const int lane = tid & 63;
    const int c0   = blockIdx.x * (4 * STRIP) + wid * STRIP;  // strip base col
    const int y0   = blockIdx.y * CHUNK;
    const size_t pbase = (size_t)blockIdx.z * (IMG_H * IMG_W);
    const float* p1 = img1 + pbase;
    const float* p2 = img2 + pbase;
    unsigned* buf = srow[wid];

    // hoisted column indices/predicates
    const int gm = c0 - RAD + lane;             // main entry (buf idx = lane)
    const bool qm = (gm >= 0 && gm < IMG_W);
    const int gt = c0 + STRIP - RAD + lane;     // tail entry (lanes 0..9)
    const bool qt = (lane < 2 * RAD) && (gt < IMG_W);

    // per-lane column weight mass for output col x1 = c0+lane (once per kernel)
    const int x1 = c0 + lane;
    float Wc = 0.f;
    #pragma unroll
    for (int d = 0; d < TAPS; ++d)
        if ((unsigned)(x1 + d - RAD) < IMG_W) Wc += gw.wf[d];

    // register ring, 11 rows deep, fp16x2:
    //   rP = (conv_h a', conv_h b')   rS = (conv_h a'^2, conv_h b'^2)   rX = (conv_h a'b', dup)
    __half2 rP[TAPS], rS[TAPS], rX[TAPS];
    const __half2 hz = __float2half2_rn(0.0f);

    // fp32 prefetch regs for next row (CENTERED; pad stays exactly 0)
    float pa, pb, pta, ptb;

    auto load_regs = [&](int r) {
        pa = pb = pta = ptb = 0.f;
        if (r >= 0 && r < IMG_H) {              // wave-uniform
            const float* r1 = p1 + (size_t)r * IMG_W;
            const float* r2 = p2 + (size_t)r * IMG_W;
            if (qm) { pa = r1[gm] - 0.5f; pb = r2[gm] - 0.5f; }
            if (qt) { pta = r1[gt] - 0.5f; ptb = r2[gt] - 0.5f; }
        }
    };

    auto store_lds = [&]() {
        WAVE_FENCE_WAR();              // don't sink this write above prior reads
        buf[lane] = h2bits(__float22half2_rn(make_float2(pa, pb)));
        if (lane < 2 * RAD)
            buf[STRIP + lane] = h2bits(__float22half2_rn(make_float2(pta, ptb)));
        WAVE_FENCE_RAW();              // don't hoist following reads above it
    };

    // packed hconv: per tap 1 ds_read_b32 + 3 hfma2 + 2 hmul2 + 1 alignbit
    auto hconv = [&](int r, __half2& oP, __half2& oS, __half2& oX) {
        __half2 hP = hz, hS = hz, hX = hz;
        if (r >= 0 && r < IMG_H) {              // wave-uniform: padded rows are zero
            #pragma unroll
            for (int d = 0; d < TAPS; ++d) {
                __half2 v  = bits2h(buf[lane + d]);       // (a', b')
                __half2 wv = bits2h(gw.w[d]);
                hP = __hfma2(wv, v, hP);
                hS = __hfma2(wv, __hmul2(v, v), hS);
                hX = __hfma2(wv, __hmul2(v, swap16(v)), hX);   // (a'b', b'a')
            }
        }
        oP = hP; oS = hS; oX = hX;
    };

    // ---- prologue: h-rows 0..9 (global rows y0-5 .. y0+4) -> ring slots 0..9
    load_regs(y0 - RAD);
    #pragma unroll
    for (int k = 0; k < TAPS - 1; ++k) {
        const int r = y0 - RAD + k;
        store_lds();
        load_regs(r + 1);              // next row's loads in flight during hconv
        hconv(r, rP[k], rS[k], rX[k]);
    }

    const float C1v = 0.0001f;  // 0.01^2
    const float C2v = 0.0009f;  // 0.03^2
    float acc = 0.f;

    // ---- main: CHUNK rows, outer RUNTIME loop (bounds live ranges — R8/R9
    // flattened this and spilled), inner static 11 (ring phase = j only)
    for (int kk = 0; kk < CHUNK; kk += TAPS) {
        #pragma unroll
        for (int j = 0; j < TAPS; ++j) {
            const int r = y0 - RAD + (TAPS - 1) + kk + j;  // staged input row
            store_lds();               // publish prefetched row r
            load_regs(r + 1);          // issue loads for row r+1 NOW
            hconv(r, rP[(j + 10) % TAPS], rS[(j + 10) % TAPS], rX[(j + 10) % TAPS]);

            const int y = y0 + kk + j; // output row
            if (y < IMG_H) {
                // packed vertical conv: 3 hfma2 per tap
                __half2 sP = hz, sS = hz, sX = hz;
                #pragma unroll
                for (int t = 0; t < TAPS; ++t) {
                    const int s = (j + t) % TAPS;          // static after unroll
                    __half2 wv = bits2h(gw.w[t]);
                    sP = __hfma2(wv, rP[s], sP);
                    sS = __hfma2(wv, rS[s], sS);
                    sX = __hfma2(wv, rX[s], sX);
                }
                // row weight mass (wave-uniform)
                float Wr = 0.f;
                #pragma unroll
                for (int t = 0; t < TAPS; ++t)
                    if ((unsigned)(y + t - RAD) < IMG_H) Wr += gw.wf[t];

                // fp32 epilogue with centering recovery (c = 0.5):
                //   mu = m + 0.5W;  sg = P + mu - 0.25W - mu^2;
                //   sg12 = P12 + 0.5(mu1+mu2) - 0.25W - mu1*mu2
                float m1  = __low2float(sP),  m2  = __high2float(sP);
                float P11 = __low2float(sS),  P22 = __high2float(sS);
                float P12 = __low2float(sX);
                float W   = Wc * Wr;
                float mu1 = fmaf(0.5f, W, m1);
                float mu2 = fmaf(0.5f, W, m2);
                float qW  = 0.25f * W;
                float mu1sq = mu1 * mu1, mu2sq = mu2 * mu2, mu12 = mu1 * mu2;
                float sg1  = P11 + mu1 - qW - mu1sq;
                float sg2  = P22 + mu2 - qW - mu2sq;
                float sg12 = P12 + 0.5f * (mu1 + mu2) - qW - mu12;
                float num = (2.f * mu12 + C1v) * (2.f * sg12 + C2v);
                float den = (mu1sq + mu2sq + C1v) * (sg1 + sg2 + C2v);
                acc += num * __builtin_amdgcn_rcpf(den);
            }
        }
    }

    // wave (64-lane) shuffle reduce -> block partials -> one atomic per block
    #pragma unroll
    for (int off = 32; off > 0; off >>= 1) acc += __shfl_down(acc, off, 64);
    if (lane == 0) wsum[wid] = acc;
    __syncthreads();                   // only block barrier in the kernel
    if (tid == 0) {
        double s = (double)wsum[0] + (double)wsum[1] + (double)wsum[2] + (double)wsum[3];
        atomicAdd(sum_ws, s);
    }
}

__global__ void ssim_finalize(const double* __restrict__ sum_ws, float* __restrict__ out) {
    out[0] = (float)(sum_ws[0] * (1.0 / (double)(16.0 * 3.0 * 512.0 * 512.0)));
}

// host fp32 -> fp16 bits, round-to-nearest-even
static unsigned short f32_to_f16_rne(float f) {
    unsigned x; __builtin_memcpy(&x, &f, 4);
    unsigned sign = (x >> 16) & 0x8000u;
    int exp = (int)((x >> 23) & 0xffu) - 127 + 15;
    unsigned man = x & 0x7fffffu;
    if (exp <= 0) return (unsigned short)sign;
    unsigned h = sign | ((unsigned)exp << 10) | (man >> 13);
    unsigned rnd = man & 0x1fffu;
    if (rnd > 0x1000u || (rnd == 0x1000u && (h & 1u))) h++;
    return (unsigned short)h;
}

extern "C" void kernel_launch(void* const* d_in, const int* in_sizes, int n_in,
                              void* d_out, int out_size, void* d_ws, size_t ws_size,
                              hipStream_t stream) {
    const float* img1 = (const float*)d_in[0];
    const float* img2 = (const float*)d_in[1];
    float* out = (float*)d_out;
    double* ws = (double*)d_ws;

    hipMemsetAsync(ws, 0, sizeof(double), stream);

    // Gaussian weights in double -> fp16 broadcast-packed + fp32 kernarg
    GaussPk gw;
    double g[TAPS], s = 0.0;
    for (int i = 0; i < TAPS; ++i) {
        double x = (double)(i - TAPS / 2);
        g[i] = exp(-(x * x) / (2.0 * 1.5 * 1.5));
        s += g[i];
    }
    for (int i = 0; i < TAPS; ++i) {
        float wf = (float)(g[i] / s);
        gw.wf[i] = wf;
        unsigned short h = f32_to_f16_rne(wf);
        gw.w[i] = (unsigned)h | ((unsigned)h << 16);
    }

    // 2 x 16 x 48 = 1536 blocks; each block = 4 autonomous 64-col wave strips
    dim3 grid(IMG_W / (4 * STRIP), (IMG_H + CHUNK - 1) / CHUNK, NPLANES);
    ssim_main<<<grid, 256, 0, stream>>>(img1, img2, ws, gw);
    ssim_finalize<<<1, 1, 0, stream>>>(ws, out);
}

// Round 11
// 154.319 us; speedup vs baseline: 1.4591x; 1.2159x over previous
//
#include <hip/hip_runtime.h>
#include <math.h>

#define IMG_H 512
#define IMG_W 512
#define NPLANES 48            // 16 * 3
#define RAD 5
#define TAPS 11
#define CHUNK 33              // multiple of 11 -> static ring phase in inner loop
#define STRIP 64              // columns per wave (one autonomous wave per strip)
#define SBUF 80               // 74 entries used (64 + 2*RAD), padded

typedef float v2f __attribute__((ext_vector_type(2)));

// Compiler-only fences for wave-private LDS (cross-lane dep invisible to alias
// analysis — R4 failed without them; HW in-order DS within a wave is fine).
#define WAVE_FENCE_WAR()  __asm__ __volatile__("" ::: "memory")
#define WAVE_FENCE_RAW()  __asm__ __volatile__("s_waitcnt lgkmcnt(0)" ::: "memory")

struct GaussW { float w[TAPS]; };

// Journal:
//  - R2: tight launch_bounds -> spill (WRITE 48KB->291MB). Keep (256,4).
//  - R3: per-row __syncthreads lockstep -> 42% VALUBusy, dur tracks staged rows.
//  - R5: wave-autonomous 64-col strips, no block barriers -> 70% busy, 77us.
//  - R6: v2f fp32, products recomputed per tap: 68.5us. pk_fp32 is 2-pass on
//    CDNA4 (157TF == scalar rate) so packing fp32 saves no datapath cycles.
//  - R7-R10: fp16x2 paths — numerics fixable (center at 0.5) but intrinsics
//    don't lower to single-pass pk_f16 (R10 busy TIME rose 46.6->62us). Dead end.
//  - R8/R9: flattening the main loop straight-line -> scratch (52-60MB). The
//    runtime outer kk loop is load-bearing (bounds live ranges).
//  - R11: algebra: SSIM needs only sigma1+sigma2 and sigma12 -> 4 convs not 5,
//    packed as TWO v2f convs: P=(a,b), Q=(a^2+b^2, ab), Q built once per
//    staged px. hconv 16->8 cy/tap, vconv 10->8. Same R6 skeleton.
__global__ __launch_bounds__(256, 4)
void ssim_main(const float* __restrict__ img1, const float* __restrict__ img2,
               double* __restrict__ sum_ws, GaussW gw) {
    __shared__ float2 sP[4][SBUF];   // per-wave row: (a, b)
    __shared__ float2 sQ[4][SBUF];   // per-wave row: (a^2+b^2, a*b)
    __shared__ float wsum[4];

    const int tid  = threadIdx.x;
    const int wid  = tid >> 6;          // wave id 0..3
    const int lane = tid & 63;
    const int c0   = blockIdx.x * (4 * STRIP) + wid * STRIP;  // strip base col
    const int y0   = blockIdx.y * CHUNK;
    const size_t pbase = (size_t)blockIdx.z * (IMG_H * IMG_W);
    const float* p1 = img1 + pbase;
    const float* p2 = img2 + pbase;
    float2* bufP = sP[wid];
    float2* bufQ = sQ[wid];

    // hoisted column indices/predicates
    const int gm = c0 - RAD + lane;             // main entry (buf idx = lane)
    const bool qm = (gm >= 0 && gm < IMG_W);
    const int gt = c0 + STRIP - RAD + lane;     // tail entry (lanes 0..9)
    const bool qt = (lane < 2 * RAD) && (gt < IMG_W);

    // register ring, 11 rows deep, v2f:
    //   rP = (conv_h a, conv_h b)     rQ = (conv_h(a^2+b^2), conv_h(ab))
    v2f rP[TAPS], rQ[TAPS];

    // fp32 prefetch regs for next row (pad stays exactly 0 == reference zero-pad)
    float pa, pb, pta, ptb;

    auto load_regs = [&](int r) {
        pa = pb = pta = ptb = 0.f;
        if (r >= 0 && r < IMG_H) {              // wave-uniform
            const float* r1 = p1 + (size_t)r * IMG_W;
            const float* r2 = p2 + (size_t)r * IMG_W;
            if (qm) { pa = r1[gm]; pb = r2[gm]; }
            if (qt) { pta = r1[gt]; ptb = r2[gt]; }
        }
    };

    auto store_lds = [&]() {
        WAVE_FENCE_WAR();              // don't sink these writes above prior reads
        bufP[lane] = make_float2(pa, pb);
        bufQ[lane] = make_float2(fmaf(pa, pa, pb * pb), pa * pb);
        if (lane < 2 * RAD) {
            bufP[STRIP + lane] = make_float2(pta, ptb);
            bufQ[STRIP + lane] = make_float2(fmaf(pta, pta, ptb * ptb), pta * ptb);
        }
        WAVE_FENCE_RAW();              // don't hoist following reads above them
    };

    // packed hconv: per tap 2 ds_read_b64 + 2 pk_fma (covers all 4 quantities)
    auto hconv = [&](int r, v2f& oP, v2f& oQ) {
        v2f aP = {0.f, 0.f}, aQ = {0.f, 0.f};
        if (r >= 0 && r < IMG_H) {              // wave-uniform: padded rows are zero
            #pragma unroll
            for (int d = 0; d < TAPS; ++d) {
                v2f P = *(const v2f*)&bufP[lane + d];
                v2f Q = *(const v2f*)&bufQ[lane + d];
                float w = gw.w[d];
                v2f w2 = {w, w};
                aP = __builtin_elementwise_fma(w2, P, aP);
                aQ = __builtin_elementwise_fma(w2, Q, aQ);
            }
        }
        oP = aP; oQ = aQ;
    };

    // ---- prologue: h-rows 0..9 (global rows y0-5 .. y0+4) -> ring slots 0..9
    load_regs(y0 - RAD);
    #pragma unroll
    for (int k = 0; k < TAPS - 1; ++k) {
        const int r = y0 - RAD + k;
        store_lds();
        load_regs(r + 1);              // next row's loads in flight during hconv
        hconv(r, rP[k], rQ[k]);
    }

    const float C1v = 0.0001f;  // 0.01^2
    const float C2v = 0.0009f;  // 0.03^2
    float acc = 0.f;

    // ---- main: CHUNK rows, outer RUNTIME loop (bounds live ranges — R8/R9
    // flattened this and spilled), inner static 11 (ring phase = j only)
    for (int kk = 0; kk < CHUNK; kk += TAPS) {
        #pragma unroll
        for (int j = 0; j < TAPS; ++j) {
            const int r = y0 - RAD + (TAPS - 1) + kk + j;  // staged input row
            store_lds();               // publish prefetched row r
            load_regs(r + 1);          // issue loads for row r+1 NOW
            hconv(r, rP[(j + 10) % TAPS], rQ[(j + 10) % TAPS]);

            const int y = y0 + kk + j; // output row
            if (y < IMG_H) {
                // packed vertical conv: 2 pk_fma per tap
                v2f vP = {0.f, 0.f}, vQ = {0.f, 0.f};
                #pragma unroll
                for (int t = 0; t < TAPS; ++t) {
                    const int s = (j + t) % TAPS;          // static after unroll
                    float w = gw.w[t];
                    v2f w2 = {w, w};
                    vP = __builtin_elementwise_fma(w2, rP[s], vP);
                    vQ = __builtin_elementwise_fma(w2, rQ[s], vQ);
                }
                // SSIM epilogue: needs only (sigma1+sigma2) and sigma12
                float mu1 = vP.x, mu2 = vP.y;
                float S   = vQ.x;    // conv(a^2 + b^2)
                float X   = vQ.y;    // conv(a*b)
                float mu1sq = mu1 * mu1, mu2sq = mu2 * mu2, mu12 = mu1 * mu2;
                float Sig = S - mu1sq - mu2sq;             // sigma1_sq + sigma2_sq
                float s12 = X - mu12;                      // sigma12
                float num = (2.f * mu12 + C1v) * (2.f * s12 + C2v);
                float den = (mu1sq + mu2sq + C1v) * (Sig + C2v);
                acc += num * __builtin_amdgcn_rcpf(den);
            }
        }
    }

    // wave (64-lane) shuffle reduce -> block partials -> one atomic per block
    #pragma unroll
    for (int off = 32; off > 0; off >>= 1) acc += __shfl_down(acc, off, 64);
    if (lane == 0) wsum[wid] = acc;
    __syncthreads();                   // only block barrier in the kernel
    if (tid == 0) {
        double s = (double)wsum[0] + (double)wsum[1] + (double)wsum[2] + (double)wsum[3];
        atomicAdd(sum_ws, s);
    }
}

__global__ void ssim_finalize(const double* __restrict__ sum_ws, float* __restrict__ out) {
    out[0] = (float)(sum_ws[0] * (1.0 / (double)(16.0 * 3.0 * 512.0 * 512.0)));
}

extern "C" void kernel_launch(void* const* d_in, const int* in_sizes, int n_in,
                              void* d_out, int out_size, void* d_ws, size_t ws_size,
                              hipStream_t stream) {
    const float* img1 = (const float*)d_in[0];
    const float* img2 = (const float*)d_in[1];
    float* out = (float*)d_out;
    double* ws = (double*)d_ws;

    // d_ws is poisoned 0xAA before every launch — zero the accumulator (async, capture-safe)
    hipMemsetAsync(ws, 0, sizeof(double), stream);

    // Gaussian weights computed on host in double, passed via kernarg (SGPRs)
    GaussW gw;
    double g[TAPS], s = 0.0;
    for (int i = 0; i < TAPS; ++i) {
        double x = (double)(i - TAPS / 2);
        g[i] = exp(-(x * x) / (2.0 * 1.5 * 1.5));
        s += g[i];
    }
    for (int i = 0; i < TAPS; ++i) gw.w[i] = (float)(g[i] / s);

    // 2 x 16 x 48 = 1536 blocks; each block = 4 autonomous 64-col wave strips
    dim3 grid(IMG_W / (4 * STRIP), (IMG_H + CHUNK - 1) / CHUNK, NPLANES);
    ssim_main<<<grid, 256, 0, stream>>>(img1, img2, ws, gw);
    ssim_finalize<<<1, 1, 0, stream>>>(ws, out);
}